// Round 11
// baseline (175.444 us; speedup 1.0000x reference)
//
#include <hip/hip_runtime.h>

#define NN 10000
#define EE 320000
#define HH 256
#define BKT 192          // per-row bucket capacity (raw deg ~Poisson(32), max ~65)

typedef __attribute__((ext_vector_type(8))) short bf16x8;
typedef __attribute__((ext_vector_type(4))) float f32x4;
typedef __attribute__((ext_vector_type(2))) float f32x2;

__device__ float bf2f(unsigned int v) {
    return __uint_as_float(v << 16);
}
__device__ unsigned short f2bf(float f) {
    unsigned int i = __float_as_uint(f);
    return (unsigned short)((i + 0x7fffu + ((i >> 16) & 1u)) >> 16);
}
// ---- software e4m3 codec (OCP-consistent; exact for normals, RNE) ----
__device__ unsigned int fp8e(float f) {
    float a = fabsf(f);
    a = fminf(a, 448.0f);
    unsigned int bits = __float_as_uint(a * __uint_as_float(0x03800000u)); // * 2^-120
    bits = bits + 0x7ffffu + ((bits >> 20) & 1u);
    unsigned int r = bits >> 20;
    if (r > 0x7eu) r = 0x7eu;
    return r | ((__float_as_uint(f) >> 24) & 0x80u);
}
__device__ float fp8d(unsigned int b) {
    float mag = __uint_as_float((b & 0x7fu) << 20) * __uint_as_float(0x7B800000u); // * 2^120
    return __uint_as_float(((b & 0x80u) << 24) | __float_as_uint(mag));
}
// ---- HW fp8->f32 decode: 4 packed e4m3 bytes -> 4 floats (2 instructions) ----
__device__ __forceinline__ void fp8dec4(unsigned int g, float* o) {
#if __has_builtin(__builtin_amdgcn_cvt_pk_f32_fp8)
    f32x2 lo = __builtin_amdgcn_cvt_pk_f32_fp8((int)g, false);
    f32x2 hi = __builtin_amdgcn_cvt_pk_f32_fp8((int)g, true);
    o[0] = lo.x; o[1] = lo.y; o[2] = hi.x; o[3] = hi.y;
#else
    #pragma unroll
    for (int j = 0; j < 4; j++) o[j] = fp8d((g >> (8 * j)) & 0xffu);
#endif
}
// ---- HW f32->fp8 encode: 2 floats -> 2 packed e4m3 bytes (1 instruction) ----
__device__ __forceinline__ unsigned int fp8e2(float a, float b) {
#if __has_builtin(__builtin_amdgcn_cvt_pk_fp8_f32)
    return (unsigned int)__builtin_amdgcn_cvt_pk_fp8_f32(a, b, 0, false);
#else
    return fp8e(a) | (fp8e(b) << 8);
#endif
}
__device__ unsigned int pk2(unsigned short a, unsigned short b) {
    return (unsigned int)a | ((unsigned int)b << 16);
}
__device__ int eload(const void* ei, int is64, int idx) {
    if (is64) return (int)(((const long long*)ei)[idx]);
    return ((const int*)ei)[idx];
}
__device__ __forceinline__ float dinv_of(int d) {
    return d > 0 ? rsqrtf((float)d) : 0.0f;
}
// wave-uniform index -> SGPR (neighbor lists are walked wave-synchronously)
__device__ __forceinline__ int rfl(int v) {
    return __builtin_amdgcn_readfirstlane(v);
}

// ---- 1. k_AB: b==0 detect flags; b in [1,65) weight swizzle (block-local
//  f32 detect); b>=65 raw edge scatter (block-local is64 detect).
//  rawcnt/cnt2 pre-zeroed by hipMemsetAsync.
__global__ void k_AB(const void* x, const void* ei, const void* W1, const void* W2,
                     int* flags, int* rawcnt, unsigned short* bucket,
                     unsigned short* W1sw, unsigned short* W2sw) {
    int b = blockIdx.x, t = threadIdx.x;
    if (b >= 65) {
        // ---- raw scatter with block-local int64 detect ----
        __shared__ int s_nz;
        if (t == 0) s_nz = 0;
        __syncthreads();
        if (t < 64) {
            const unsigned int* eu = (const unsigned int*)ei;
            for (int k = t; k < 256; k += 64)
                if (eu[2 * k + 1] != 0) atomicOr(&s_nz, 1);
        }
        __syncthreads();
        int is64 = s_nz ? 0 : 1;
        int e = (b - 65) * 256 + t;      // exactly EE threads
        if (e >= EE) return;
        int r = eload(ei, is64, e);
        int c = eload(ei, is64, EE + e);
        if (r < 0 || r >= NN || c < 0 || c >= NN) return;
        int slot = atomicAdd(&rawcnt[r], 1);
        if (slot < BKT) bucket[(size_t)r * BKT + slot] = (unsigned short)c;
        return;
    }
    if (b == 0) {
        __shared__ int s0, s1;
        if (t == 0) { s0 = 0; s1 = 0; }
        __syncthreads();
        if (t < 64) {
            const unsigned int* eu = (const unsigned int*)ei;
            const unsigned int* xu = (const unsigned int*)x;
            for (int k = t; k < 256; k += 64)
                if (eu[2 * k + 1] != 0) atomicOr(&s0, 1);
            unsigned int lo = xu[t] & 0xffffu;
            unsigned int ex = (lo >> 7) & 0xffu;
            if (lo == 0u || (ex >= 90u && ex <= 150u)) atomicAdd(&s1, 1);
        }
        __syncthreads();
        if (t == 0) {
            flags[0] = s0 ? 0 : 1;          // edge_index is int64
            flags[1] = (s1 >= 56) ? 0 : 1;  // floats are f32
        }
        return;
    }
    // ---- weight swizzle with block-local f32 detect ----
    __shared__ int plaus;
    if (t == 0) plaus = 0;
    __syncthreads();
    if (t < 64) {
        unsigned int lo = ((const unsigned int*)x)[t] & 0xffffu;
        unsigned int ex = (lo >> 7) & 0xffu;
        if (lo == 0u || (ex >= 90u && ex <= 150u)) atomicAdd(&plaus, 1);
    }
    __syncthreads();
    int f32io = (plaus >= 56) ? 0 : 1;
    int vb = b - 1;                      // 0..63
    const void* W = (vb < 32) ? W1 : W2;
    unsigned short* O = (vb < 32) ? W1sw : W2sw;
    int g = ((vb < 32) ? vb : vb - 32) * 256 + t;   // 8192 groups of 8
    int gl = g & 63;
    int n = (g >> 6) & 15;
    int ks = g >> 10;
    int coln = n * 16 + (gl & 15);
    int krow = ks * 32 + ((gl >> 4) & 3) * 8;
    unsigned short v[8];
    if (f32io) {
        const float* Wf = (const float*)W;
        #pragma unroll
        for (int j = 0; j < 8; j++) v[j] = f2bf(Wf[(size_t)(krow + j) * HH + coln]);
    } else {
        const unsigned short* Wh = (const unsigned short*)W;
        #pragma unroll
        for (int j = 0; j < 8; j++) v[j] = Wh[(size_t)(krow + j) * HH + coln];
    }
    uint4 p;
    p.x = pk2(v[0], v[1]); p.y = pk2(v[2], v[3]);
    p.z = pk2(v[4], v[5]); p.w = pk2(v[6], v[7]);
    *(uint4*)(O + (size_t)g * 8) = p;
}

// ---- 2. k_DG: blocks [0,2500) O(d) LDS-bitmap dedupe + degree counts;
//  blocks [2500,3125) MFMA GEMM Y = x @ W1 (LDS-staged A, HW fp8 encode).
__global__ void k_DG(const void* x, const unsigned short* __restrict__ W1sw,
                     const int* flags, const int* rawcnt, int* cnt2,
                     unsigned short* bucket, unsigned char* Yf8, void* Oout) {
    __shared__ unsigned int bm[4][316];
    __shared__ int cnt[4];
    __shared__ unsigned short As[16][264];   // +8 pad
    int b = blockIdx.x;
    int tid = threadIdx.x;
    if (b < 2500) {
        // ---- dedupe: 4 rows/block, one wave each, wave-synchronous ----
        int wave = tid >> 6;
        int lane = tid & 63;
        int i = b * 4 + wave;
        int d = rawcnt[i];
        if (d > BKT) d = BKT;
        for (int t = lane; t < 313; t += 64) bm[wave][t] = 0u;
        if (lane == 0) cnt[wave] = 0;
        unsigned short* bp = bucket + (size_t)i * BKT;
        int cvals[3];
        int nt = 0;
        for (int t = lane; t < d; t += 64) cvals[nt++] = (int)bp[t];
        for (int k = 0; k < nt; k++) {
            int c = cvals[k];
            unsigned int m = 1u << (c & 31);
            unsigned int old = atomicOr(&bm[wave][c >> 5], m);
            if (!(old & m)) {
                int p = atomicAdd(&cnt[wave], 1);
                bp[p] = (unsigned short)c;
                atomicAdd(&cnt2[2 * c + 1], 1);      // deg_c
            }
        }
        if (lane == 0) atomicExch(&cnt2[2 * i], cnt[wave]);  // deg_r
        return;
    }
    // ---- GEMM branch ----
    int r0 = (b - 2500) * 16;
    int af32 = flags[1];
    {
        int row = tid >> 4, seg = tid & 15;
        if (af32) {
            const float* ap = (const float*)x + (size_t)(r0 + row) * HH + seg * 16;
            unsigned short v[16];
            #pragma unroll
            for (int j = 0; j < 16; j += 4) {
                float4 q = *(const float4*)(ap + j);
                v[j] = f2bf(q.x); v[j + 1] = f2bf(q.y);
                v[j + 2] = f2bf(q.z); v[j + 3] = f2bf(q.w);
            }
            uint4 p0, p1;
            p0.x = pk2(v[0], v[1]);   p0.y = pk2(v[2], v[3]);
            p0.z = pk2(v[4], v[5]);   p0.w = pk2(v[6], v[7]);
            p1.x = pk2(v[8], v[9]);   p1.y = pk2(v[10], v[11]);
            p1.z = pk2(v[12], v[13]); p1.w = pk2(v[14], v[15]);
            *(uint4*)&As[row][seg * 16] = p0;
            *(uint4*)&As[row][seg * 16 + 8] = p1;
        } else {
            const unsigned short* ap = (const unsigned short*)x + (size_t)(r0 + row) * HH + seg * 16;
            *(uint4*)&As[row][seg * 16] = *(const uint4*)ap;
            *(uint4*)&As[row][seg * 16 + 8] = *(const uint4*)(ap + 8);
        }
    }
    __syncthreads();
    int wv = tid >> 6;
    int lane = tid & 63;
    int quad = lane >> 4;
    int l16 = lane & 15;
    f32x4 acc[4] = {{0,0,0,0},{0,0,0,0},{0,0,0,0},{0,0,0,0}};
    for (int ks = 0; ks < 8; ks++) {
        bf16x8 af = *(const bf16x8*)&As[l16][ks * 32 + quad * 8];
        #pragma unroll
        for (int t = 0; t < 4; t++) {
            int n = wv * 4 + t;
            bf16x8 bf = *(const bf16x8*)(W1sw + ((size_t)(ks * 16 + n) * 64 + lane) * 8);
            acc[t] = __builtin_amdgcn_mfma_f32_16x16x32_bf16(af, bf, acc[t], 0, 0, 0);
        }
    }
    size_t chunkW = (size_t)NN * HH;
    #pragma unroll
    for (int t = 0; t < 4; t++) {
        int cn = (wv * 4 + t) * 16 + l16;
        #pragma unroll
        for (int r = 0; r < 4; r += 2) {
            int row = r0 + quad * 4 + r;
            float v0 = acc[t][r], v1 = acc[t][r + 1];
            unsigned int pk = fp8e2(v0, v1);
            size_t idx0 = (size_t)row * HH + cn;
            size_t idx1 = idx0 + HH;
            Yf8[idx0] = (unsigned char)(pk & 0xffu);
            Yf8[idx1] = (unsigned char)((pk >> 8) & 0xffu);
            if (af32) {
                ((float*)Oout)[2 * chunkW + idx0] = v0;
                ((float*)Oout)[2 * chunkW + idx1] = v1;
            } else {
                ((unsigned short*)Oout)[2 * chunkW + idx0] = f2bf(v0);
                ((unsigned short*)Oout)[2 * chunkW + idx1] = f2bf(v1);
            }
        }
    }
}

// ---- 3. k_CD: FUSED mid layer + stacked G GEMM. 1250 blocks x 512 thr;
//  block owns 8 node-rows, 1 row/wave, unroll-16 gather (2 dependent
//  batches per ~31-neighbor row); neighbor indices scalarized.
//  G tables written PRE-SCALED; G1 stash (chunk 1) stays unscaled.
__global__ __launch_bounds__(512, 4) void k_CD(
        const unsigned char* __restrict__ Yf8,
        const unsigned short* __restrict__ bucket,
        const int* __restrict__ cnt2, const unsigned short* __restrict__ W2sw,
        const void* __restrict__ b1, const int* __restrict__ flags,
        unsigned char* G12f8, void* Oout) {
    __shared__ unsigned short Hs[16][264];   // +8 pad; rows 0..7 h1, 8..15 h2
    __shared__ float wsc[16];                // dinv_r (0..7) / dinv_c (8..15)
    int tid = threadIdx.x;
    int wave = tid >> 6;
    int lane = tid & 63;
    int fb = lane * 4;
    int bbase = blockIdx.x * 8;
    int f32io = flags[1];
    size_t chunkW = (size_t)NN * HH;
    float bv[4];
    if (f32io) {
        const float* bp = (const float*)b1 + fb;
        #pragma unroll
        for (int k = 0; k < 4; k++) bv[k] = bp[k];
    } else {
        uint2 br = *(const uint2*)((const unsigned short*)b1 + fb);
        bv[0] = bf2f(br.x & 0xffffu); bv[1] = bf2f(br.x >> 16);
        bv[2] = bf2f(br.y & 0xffffu); bv[3] = bf2f(br.y >> 16);
    }
    // ---- phase 1: SpMM, one row per wave, unroll 16, scalarized indices ----
    {
        int i = bbase + wave;
        float a1[4] = {0, 0, 0, 0};
        float a2[4] = {0, 0, 0, 0};
        int2 ddi = *(const int2*)(cnt2 + 2 * i);
        int n = ddi.x;
        const unsigned short* cp = bucket + (size_t)i * BKT;
        int t = 0;
        for (; t + 16 <= n; t += 16) {
            ushort4 q0 = *(const ushort4*)(cp + t);
            ushort4 q1 = *(const ushort4*)(cp + t + 4);
            ushort4 q2 = *(const ushort4*)(cp + t + 8);
            ushort4 q3 = *(const ushort4*)(cp + t + 12);
            int cx[16];
            cx[0]  = rfl((int)q0.x); cx[1]  = rfl((int)q0.y);
            cx[2]  = rfl((int)q0.z); cx[3]  = rfl((int)q0.w);
            cx[4]  = rfl((int)q1.x); cx[5]  = rfl((int)q1.y);
            cx[6]  = rfl((int)q1.z); cx[7]  = rfl((int)q1.w);
            cx[8]  = rfl((int)q2.x); cx[9]  = rfl((int)q2.y);
            cx[10] = rfl((int)q2.z); cx[11] = rfl((int)q2.w);
            cx[12] = rfl((int)q3.x); cx[13] = rfl((int)q3.y);
            cx[14] = rfl((int)q3.z); cx[15] = rfl((int)q3.w);
            unsigned int gv[16];
            #pragma unroll
            for (int j = 0; j < 16; j++)
                gv[j] = *(const unsigned int*)(Yf8 + (size_t)cx[j] * 256 + fb);
            float wx[16], wy[16];
            #pragma unroll
            for (int j = 0; j < 16; j++) {
                int2 dd = *(const int2*)(cnt2 + 2 * cx[j]);
                wx[j] = dinv_of(dd.x);
                wy[j] = dinv_of(dd.y);
            }
            #pragma unroll
            for (int j = 0; j < 16; j++) {
                float y[4];
                fp8dec4(gv[j], y);
                #pragma unroll
                for (int k = 0; k < 4; k++) {
                    a1[k] += wx[j] * y[k];
                    a2[k] += wy[j] * y[k];
                }
            }
        }
        for (; t + 8 <= n; t += 8) {
            ushort4 ca = *(const ushort4*)(cp + t);
            ushort4 cb = *(const ushort4*)(cp + t + 4);
            int cx[8];
            cx[0] = rfl((int)ca.x); cx[1] = rfl((int)ca.y);
            cx[2] = rfl((int)ca.z); cx[3] = rfl((int)ca.w);
            cx[4] = rfl((int)cb.x); cx[5] = rfl((int)cb.y);
            cx[6] = rfl((int)cb.z); cx[7] = rfl((int)cb.w);
            unsigned int gv[8];
            #pragma unroll
            for (int j = 0; j < 8; j++)
                gv[j] = *(const unsigned int*)(Yf8 + (size_t)cx[j] * 256 + fb);
            float wx[8], wy[8];
            #pragma unroll
            for (int j = 0; j < 8; j++) {
                int2 dd = *(const int2*)(cnt2 + 2 * cx[j]);
                wx[j] = dinv_of(dd.x);
                wy[j] = dinv_of(dd.y);
            }
            #pragma unroll
            for (int j = 0; j < 8; j++) {
                float y[4];
                fp8dec4(gv[j], y);
                #pragma unroll
                for (int k = 0; k < 4; k++) {
                    a1[k] += wx[j] * y[k];
                    a2[k] += wy[j] * y[k];
                }
            }
        }
        for (; t + 4 <= n; t += 4) {
            ushort4 c4 = *(const ushort4*)(cp + t);
            int cx[4];
            cx[0] = rfl((int)c4.x); cx[1] = rfl((int)c4.y);
            cx[2] = rfl((int)c4.z); cx[3] = rfl((int)c4.w);
            unsigned int gv[4];
            #pragma unroll
            for (int j = 0; j < 4; j++)
                gv[j] = *(const unsigned int*)(Yf8 + (size_t)cx[j] * 256 + fb);
            float wx[4], wy[4];
            #pragma unroll
            for (int j = 0; j < 4; j++) {
                int2 dd = *(const int2*)(cnt2 + 2 * cx[j]);
                wx[j] = dinv_of(dd.x);
                wy[j] = dinv_of(dd.y);
            }
            #pragma unroll
            for (int j = 0; j < 4; j++) {
                float y[4];
                fp8dec4(gv[j], y);
                #pragma unroll
                for (int k = 0; k < 4; k++) {
                    a1[k] += wx[j] * y[k];
                    a2[k] += wy[j] * y[k];
                }
            }
        }
        for (; t < n; t++) {
            int c = rfl((int)cp[t]);
            int2 dd = *(const int2*)(cnt2 + 2 * c);
            float wx = dinv_of(dd.x);
            float wy = dinv_of(dd.y);
            unsigned int g = *(const unsigned int*)(Yf8 + (size_t)c * 256 + fb);
            float y[4];
            fp8dec4(g, y);
            #pragma unroll
            for (int k = 0; k < 4; k++) {
                a1[k] += wx * y[k];
                a2[k] += wy * y[k];
            }
        }
        float wiix = dinv_of(ddi.x);
        float wiiy = dinv_of(ddi.y);
        if (lane == 0) { wsc[wave] = wiix; wsc[8 + wave] = wiiy; }
        float yv[4];
        if (f32io) {
            const float* sp = (const float*)Oout + 2 * chunkW + (size_t)i * HH + fb;
            #pragma unroll
            for (int k = 0; k < 4; k++) yv[k] = sp[k];
        } else {
            uint2 yi = *(const uint2*)((const unsigned short*)Oout + 2 * chunkW + (size_t)i * HH + fb);
            yv[0] = bf2f(yi.x & 0xffffu); yv[1] = bf2f(yi.x >> 16);
            yv[2] = bf2f(yi.y & 0xffffu); yv[3] = bf2f(yi.y >> 16);
        }
        float h1[4], h2[4];
        #pragma unroll
        for (int k = 0; k < 4; k++) {
            h1[k] = fmaxf(0.f, yv[k] - wiix * a1[k] + bv[k]);
            h2[k] = fmaxf(0.f, wiiy * a2[k] + bv[k]);
        }
        uint2 p1, p2;
        p1.x = pk2(f2bf(h1[0]), f2bf(h1[1])); p1.y = pk2(f2bf(h1[2]), f2bf(h1[3]));
        p2.x = pk2(f2bf(h2[0]), f2bf(h2[1])); p2.y = pk2(f2bf(h2[2]), f2bf(h2[3]));
        *(uint2*)&Hs[wave][fb] = p1;
        *(uint2*)&Hs[8 + wave][fb] = p2;
    }
    __syncthreads();
    // ---- phase 2: one 16x256 MFMA GEMM of stacked [h1;h2] vs W2 ----
    int quad = lane >> 4;
    int l16 = lane & 15;
    f32x4 acc[2] = {{0,0,0,0},{0,0,0,0}};
    for (int ks = 0; ks < 8; ks++) {
        bf16x8 af = *(const bf16x8*)&Hs[l16][ks * 32 + quad * 8];
        #pragma unroll
        for (int t = 0; t < 2; t++) {
            int n = wave * 2 + t;
            bf16x8 bf = *(const bf16x8*)(W2sw + ((size_t)(ks * 16 + n) * 64 + lane) * 8);
            acc[t] = __builtin_amdgcn_mfma_f32_16x16x32_bf16(af, bf, acc[t], 0, 0, 0);
        }
    }
    #pragma unroll
    for (int t = 0; t < 2; t++) {
        int cn = (wave * 2 + t) * 16 + l16;
        #pragma unroll
        for (int r = 0; r < 4; r += 2) {
            int row16 = quad * 4 + r;
            float v0 = acc[t][r], v1 = acc[t][r + 1];
            unsigned int pk = fp8e2(wsc[row16] * v0, wsc[row16 + 1] * v1);
            if (row16 < 8) {                 // G1 rows: scaled table + unscaled stash
                int node = bbase + row16;
                G12f8[(size_t)node * 512 + cn] = (unsigned char)(pk & 0xffu);
                G12f8[(size_t)(node + 1) * 512 + cn] = (unsigned char)((pk >> 8) & 0xffu);
                size_t idx0 = (size_t)node * HH + cn;
                size_t idx1 = idx0 + HH;
                if (f32io) {
                    ((float*)Oout)[chunkW + idx0] = v0;
                    ((float*)Oout)[chunkW + idx1] = v1;
                } else {
                    ((unsigned short*)Oout)[chunkW + idx0] = f2bf(v0);
                    ((unsigned short*)Oout)[chunkW + idx1] = f2bf(v1);
                }
            } else {                         // G2 rows: scaled table
                int node = bbase + row16 - 8;
                G12f8[(size_t)node * 512 + 256 + cn] = (unsigned char)(pk & 0xffu);
                G12f8[(size_t)(node + 1) * 512 + 256 + cn] = (unsigned char)((pk >> 8) & 0xffu);
            }
        }
    }
}

// ---- 4. k_E: fused final layer (pure-sum gather on pre-scaled tables,
//  unroll-16, scalarized neighbor indices).
__global__ __launch_bounds__(256, 4) void k_E(
        const unsigned char* __restrict__ G12f8,
        const unsigned short* __restrict__ bucket,
        const int* __restrict__ cnt2, const void* __restrict__ bias,
        const int* __restrict__ flags, void* Oout) {
    int wave = threadIdx.x >> 6;
    int lane = threadIdx.x & 63;
    int half = lane >> 5;
    int sub = lane & 31;
    int fb = sub * 8;
    int goff = half * 256 + fb;
    int i = blockIdx.x * 4 + wave;
    float acc[8] = {0, 0, 0, 0, 0, 0, 0, 0};
    int2 ddi = *(const int2*)(cnt2 + 2 * i);
    int n = ddi.x;
    const unsigned short* cp = bucket + (size_t)i * BKT;
    int t = 0;
    for (; t + 16 <= n; t += 16) {
        ushort4 q0 = *(const ushort4*)(cp + t);
        ushort4 q1 = *(const ushort4*)(cp + t + 4);
        ushort4 q2 = *(const ushort4*)(cp + t + 8);
        ushort4 q3 = *(const ushort4*)(cp + t + 12);
        int cx[16];
        cx[0]  = rfl((int)q0.x); cx[1]  = rfl((int)q0.y);
        cx[2]  = rfl((int)q0.z); cx[3]  = rfl((int)q0.w);
        cx[4]  = rfl((int)q1.x); cx[5]  = rfl((int)q1.y);
        cx[6]  = rfl((int)q1.z); cx[7]  = rfl((int)q1.w);
        cx[8]  = rfl((int)q2.x); cx[9]  = rfl((int)q2.y);
        cx[10] = rfl((int)q2.z); cx[11] = rfl((int)q2.w);
        cx[12] = rfl((int)q3.x); cx[13] = rfl((int)q3.y);
        cx[14] = rfl((int)q3.z); cx[15] = rfl((int)q3.w);
        uint2 gv[16];
        #pragma unroll
        for (int j = 0; j < 16; j++)
            gv[j] = *(const uint2*)(G12f8 + (size_t)cx[j] * 512 + goff);
        #pragma unroll
        for (int j = 0; j < 16; j++) {
            float y[4], y2[4];
            fp8dec4(gv[j].x, y);
            fp8dec4(gv[j].y, y2);
            #pragma unroll
            for (int k = 0; k < 4; k++) {
                acc[k]     += y[k];
                acc[4 + k] += y2[k];
            }
        }
    }
    for (; t + 8 <= n; t += 8) {
        ushort4 ca = *(const ushort4*)(cp + t);
        ushort4 cb = *(const ushort4*)(cp + t + 4);
        int cx[8];
        cx[0] = rfl((int)ca.x); cx[1] = rfl((int)ca.y);
        cx[2] = rfl((int)ca.z); cx[3] = rfl((int)ca.w);
        cx[4] = rfl((int)cb.x); cx[5] = rfl((int)cb.y);
        cx[6] = rfl((int)cb.z); cx[7] = rfl((int)cb.w);
        uint2 gv[8];
        #pragma unroll
        for (int j = 0; j < 8; j++)
            gv[j] = *(const uint2*)(G12f8 + (size_t)cx[j] * 512 + goff);
        #pragma unroll
        for (int j = 0; j < 8; j++) {
            float y[4], y2[4];
            fp8dec4(gv[j].x, y);
            fp8dec4(gv[j].y, y2);
            #pragma unroll
            for (int k = 0; k < 4; k++) {
                acc[k]     += y[k];
                acc[4 + k] += y2[k];
            }
        }
    }
    for (; t + 4 <= n; t += 4) {
        ushort4 c4 = *(const ushort4*)(cp + t);
        int cx[4];
        cx[0] = rfl((int)c4.x); cx[1] = rfl((int)c4.y);
        cx[2] = rfl((int)c4.z); cx[3] = rfl((int)c4.w);
        uint2 gv[4];
        #pragma unroll
        for (int j = 0; j < 4; j++)
            gv[j] = *(const uint2*)(G12f8 + (size_t)cx[j] * 512 + goff);
        #pragma unroll
        for (int j = 0; j < 4; j++) {
            float y[4], y2[4];
            fp8dec4(gv[j].x, y);
            fp8dec4(gv[j].y, y2);
            #pragma unroll
            for (int k = 0; k < 4; k++) {
                acc[k]     += y[k];
                acc[4 + k] += y2[k];
            }
        }
    }
    for (; t < n; t++) {
        int c = rfl((int)cp[t]);
        uint2 g = *(const uint2*)(G12f8 + (size_t)c * 512 + goff);
        float y[4], y2[4];
        fp8dec4(g.x, y);
        fp8dec4(g.y, y2);
        #pragma unroll
        for (int k = 0; k < 4; k++) {
            acc[k]     += y[k];
            acc[4 + k] += y2[k];
        }
    }
    int f32io = flags[1];
    float bv[8];
    if (f32io) {
        const float* bp = (const float*)bias + fb;
        #pragma unroll
        for (int k = 0; k < 8; k++) bv[k] = bp[k];
    } else {
        uint4 br = *(const uint4*)((const unsigned short*)bias + fb);
        bv[0] = bf2f(br.x & 0xffffu); bv[1] = bf2f(br.x >> 16);
        bv[2] = bf2f(br.y & 0xffffu); bv[3] = bf2f(br.y >> 16);
        bv[4] = bf2f(br.z & 0xffffu); bv[5] = bf2f(br.z >> 16);
        bv[6] = bf2f(br.w & 0xffffu); bv[7] = bf2f(br.w >> 16);
    }
    size_t base = (size_t)i * HH + fb;
    size_t chunkW = (size_t)NN * HH;
    float z[8];
    if (half == 0) {            // z1 = G1[i] - wr_i*sum + b -> chunk 1
        float wiix = dinv_of(ddi.x);
        float gvv[8];
        if (f32io) {
            const float* sp = (const float*)Oout + chunkW + base;
            #pragma unroll
            for (int k = 0; k < 8; k++) gvv[k] = sp[k];
        } else {
            uint4 gi = *(const uint4*)((const unsigned short*)Oout + chunkW + base);
            gvv[0] = bf2f(gi.x & 0xffffu); gvv[1] = bf2f(gi.x >> 16);
            gvv[2] = bf2f(gi.y & 0xffffu); gvv[3] = bf2f(gi.y >> 16);
            gvv[4] = bf2f(gi.z & 0xffffu); gvv[5] = bf2f(gi.z >> 16);
            gvv[6] = bf2f(gi.w & 0xffffu); gvv[7] = bf2f(gi.w >> 16);
        }
        #pragma unroll
        for (int k = 0; k < 8; k++) z[k] = gvv[k] - wiix * acc[k] + bv[k];
        if (f32io) {
            float* o = (float*)Oout + chunkW + base;
            *(float4*)o = make_float4(z[0], z[1], z[2], z[3]);
            *(float4*)(o + 4) = make_float4(z[4], z[5], z[6], z[7]);
        } else {
            uint4 p;
            p.x = pk2(f2bf(z[0]), f2bf(z[1])); p.y = pk2(f2bf(z[2]), f2bf(z[3]));
            p.z = pk2(f2bf(z[4]), f2bf(z[5])); p.w = pk2(f2bf(z[6]), f2bf(z[7]));
            *(uint4*)((unsigned short*)Oout + chunkW + base) = p;
        }
    } else {                    // z2 = wc_i*sum + b -> chunks 0, 2
        float wiiy = dinv_of(ddi.y);
        #pragma unroll
        for (int k = 0; k < 8; k++) z[k] = wiiy * acc[k] + bv[k];
        if (f32io) {
            float* o0 = (float*)Oout + base;
            float* o2 = (float*)Oout + 2 * chunkW + base;
            float4 pa = make_float4(z[0], z[1], z[2], z[3]);
            float4 pb = make_float4(z[4], z[5], z[6], z[7]);
            *(float4*)o0 = pa; *(float4*)(o0 + 4) = pb;
            *(float4*)o2 = pa; *(float4*)(o2 + 4) = pb;
        } else {
            uint4 p;
            p.x = pk2(f2bf(z[0]), f2bf(z[1])); p.y = pk2(f2bf(z[2]), f2bf(z[3]));
            p.z = pk2(f2bf(z[4]), f2bf(z[5])); p.w = pk2(f2bf(z[6]), f2bf(z[7]));
            *(uint4*)((unsigned short*)Oout + base) = p;
            *(uint4*)((unsigned short*)Oout + 2 * chunkW + base) = p;
        }
    }
}

extern "C" void kernel_launch(void* const* d_in, const int* in_sizes, int n_in,
                              void* d_out, int out_size, void* d_ws, size_t ws_size,
                              hipStream_t stream) {
    const void* x = 0; const void* ei = 0;
    const void* W1 = 0; const void* b1 = 0; const void* W2 = 0; const void* b2 = 0;
    for (int i = 0; i < n_in; i++) {
        int s = in_sizes[i];
        if (s == NN * HH) x = d_in[i];
        else if (s == 2 * EE) ei = d_in[i];
        else if (s == HH * HH) { if (!W1) W1 = d_in[i]; else W2 = d_in[i]; }
        else if (s == HH) { if (!b1) b1 = d_in[i]; else b2 = d_in[i]; }
    }

    char* ws = (char*)d_ws;
    size_t off = 0;
    int* flags = (int*)(ws + off); off += 256;
    int* rawcnt = (int*)(ws + off); off += 40960;   // raw per-row counts (padded)
    int* cnt2 = (int*)(ws + off); off += 81920;     // interleaved deg_r/deg_c (padded)
    unsigned short* bucket = (unsigned short*)(ws + off); off += (size_t)NN * BKT * 2;
    unsigned short* W1sw = (unsigned short*)(ws + off); off += (size_t)HH * HH * 2;
    unsigned short* W2sw = (unsigned short*)(ws + off); off += (size_t)HH * HH * 2;
    unsigned char* Yf8 = (unsigned char*)(ws + off); off += (size_t)NN * 256;
    unsigned char* G12f8 = (unsigned char*)(ws + off); off += (size_t)NN * 512;
    // total ~12 MB

    // 0. zero rawcnt+cnt2 (contiguous 120 KB; stream-ordered, graph-capturable)
    hipMemsetAsync(rawcnt, 0, 40960 + 81920, stream);
    // 1. detect + weight swizzle (self-detect) || raw edge scatter (self-detect)
    k_AB<<<65 + EE / 256, 256, 0, stream>>>(x, ei, W1, W2, flags, rawcnt, bucket,
                                            W1sw, W2sw);
    // 2. dedupe + degree counts || GEMM Y = x@W1 (fp8 table + stash)
    k_DG<<<2500 + 625, 256, 0, stream>>>(x, W1sw, flags, rawcnt, cnt2, bucket,
                                         Yf8, d_out);
    // 3. FUSED mid layer + stacked G GEMM (1 row/wave, unroll-16)
    k_CD<<<NN / 8, 512, 0, stream>>>(Yf8, bucket, cnt2, W2sw, b1, flags, G12f8, d_out);
    // 4. fused final layer (pure-sum gather, unroll-16)
    k_E<<<NN / 4, 256, 0, stream>>>(G12f8, bucket, cnt2, b2, flags, d_out);
}

// Round 13
// 171.680 us; speedup vs baseline: 1.0219x; 1.0219x over previous
//
#include <hip/hip_runtime.h>

#define NN 10000
#define EE 320000
#define HH 256
#define BKT 192          // per-row bucket capacity (raw deg ~Poisson(32), max ~65)

typedef __attribute__((ext_vector_type(8))) short bf16x8;
typedef __attribute__((ext_vector_type(4))) float f32x4;
typedef __attribute__((ext_vector_type(2))) float f32x2;

__device__ float bf2f(unsigned int v) {
    return __uint_as_float(v << 16);
}
__device__ unsigned short f2bf(float f) {
    unsigned int i = __float_as_uint(f);
    return (unsigned short)((i + 0x7fffu + ((i >> 16) & 1u)) >> 16);
}
// ---- software e4m3 codec (OCP-consistent; exact for normals, RNE) ----
__device__ unsigned int fp8e(float f) {
    float a = fabsf(f);
    a = fminf(a, 448.0f);
    unsigned int bits = __float_as_uint(a * __uint_as_float(0x03800000u)); // * 2^-120
    bits = bits + 0x7ffffu + ((bits >> 20) & 1u);
    unsigned int r = bits >> 20;
    if (r > 0x7eu) r = 0x7eu;
    return r | ((__float_as_uint(f) >> 24) & 0x80u);
}
__device__ float fp8d(unsigned int b) {
    float mag = __uint_as_float((b & 0x7fu) << 20) * __uint_as_float(0x7B800000u); // * 2^120
    return __uint_as_float(((b & 0x80u) << 24) | __float_as_uint(mag));
}
// ---- HW fp8->f32 decode: 4 packed e4m3 bytes -> 4 floats (2 instructions) ----
__device__ __forceinline__ void fp8dec4(unsigned int g, float* o) {
#if __has_builtin(__builtin_amdgcn_cvt_pk_f32_fp8)
    f32x2 lo = __builtin_amdgcn_cvt_pk_f32_fp8((int)g, false);
    f32x2 hi = __builtin_amdgcn_cvt_pk_f32_fp8((int)g, true);
    o[0] = lo.x; o[1] = lo.y; o[2] = hi.x; o[3] = hi.y;
#else
    #pragma unroll
    for (int j = 0; j < 4; j++) o[j] = fp8d((g >> (8 * j)) & 0xffu);
#endif
}
// ---- HW f32->fp8 encode: 2 floats -> 2 packed e4m3 bytes (1 instruction) ----
__device__ __forceinline__ unsigned int fp8e2(float a, float b) {
#if __has_builtin(__builtin_amdgcn_cvt_pk_fp8_f32)
    return (unsigned int)__builtin_amdgcn_cvt_pk_fp8_f32(a, b, 0, false);
#else
    return fp8e(a) | (fp8e(b) << 8);
#endif
}
__device__ unsigned int pk2(unsigned short a, unsigned short b) {
    return (unsigned int)a | ((unsigned int)b << 16);
}
__device__ int eload(const void* ei, int is64, int idx) {
    if (is64) return (int)(((const long long*)ei)[idx]);
    return ((const int*)ei)[idx];
}
__device__ __forceinline__ float dinv_of(int d) {
    return d > 0 ? rsqrtf((float)d) : 0.0f;
}
// wave-uniform index -> SGPR (neighbor lists are walked wave-synchronously)
__device__ __forceinline__ int rfl(int v) {
    return __builtin_amdgcn_readfirstlane(v);
}

// ---- 1. k_AB: b==0 detect flags; b in [1,65) weight swizzle (block-local
//  f32 detect); b>=65 raw edge scatter (block-local is64 detect).
//  rawcnt/cnt2 pre-zeroed by hipMemsetAsync.
__global__ void k_AB(const void* x, const void* ei, const void* W1, const void* W2,
                     int* flags, int* rawcnt, unsigned short* bucket,
                     unsigned short* W1sw, unsigned short* W2sw) {
    int b = blockIdx.x, t = threadIdx.x;
    if (b >= 65) {
        // ---- raw scatter with block-local int64 detect ----
        __shared__ int s_nz;
        if (t == 0) s_nz = 0;
        __syncthreads();
        if (t < 64) {
            const unsigned int* eu = (const unsigned int*)ei;
            for (int k = t; k < 256; k += 64)
                if (eu[2 * k + 1] != 0) atomicOr(&s_nz, 1);
        }
        __syncthreads();
        int is64 = s_nz ? 0 : 1;
        int e = (b - 65) * 256 + t;      // exactly EE threads
        if (e >= EE) return;
        int r = eload(ei, is64, e);
        int c = eload(ei, is64, EE + e);
        if (r < 0 || r >= NN || c < 0 || c >= NN) return;
        int slot = atomicAdd(&rawcnt[r], 1);
        if (slot < BKT) bucket[(size_t)r * BKT + slot] = (unsigned short)c;
        return;
    }
    if (b == 0) {
        __shared__ int s0, s1;
        if (t == 0) { s0 = 0; s1 = 0; }
        __syncthreads();
        if (t < 64) {
            const unsigned int* eu = (const unsigned int*)ei;
            const unsigned int* xu = (const unsigned int*)x;
            for (int k = t; k < 256; k += 64)
                if (eu[2 * k + 1] != 0) atomicOr(&s0, 1);
            unsigned int lo = xu[t] & 0xffffu;
            unsigned int ex = (lo >> 7) & 0xffu;
            if (lo == 0u || (ex >= 90u && ex <= 150u)) atomicAdd(&s1, 1);
        }
        __syncthreads();
        if (t == 0) {
            flags[0] = s0 ? 0 : 1;          // edge_index is int64
            flags[1] = (s1 >= 56) ? 0 : 1;  // floats are f32
        }
        return;
    }
    // ---- weight swizzle with block-local f32 detect ----
    __shared__ int plaus;
    if (t == 0) plaus = 0;
    __syncthreads();
    if (t < 64) {
        unsigned int lo = ((const unsigned int*)x)[t] & 0xffffu;
        unsigned int ex = (lo >> 7) & 0xffu;
        if (lo == 0u || (ex >= 90u && ex <= 150u)) atomicAdd(&plaus, 1);
    }
    __syncthreads();
    int f32io = (plaus >= 56) ? 0 : 1;
    int vb = b - 1;                      // 0..63
    const void* W = (vb < 32) ? W1 : W2;
    unsigned short* O = (vb < 32) ? W1sw : W2sw;
    int g = ((vb < 32) ? vb : vb - 32) * 256 + t;   // 8192 groups of 8
    int gl = g & 63;
    int n = (g >> 6) & 15;
    int ks = g >> 10;
    int coln = n * 16 + (gl & 15);
    int krow = ks * 32 + ((gl >> 4) & 3) * 8;
    unsigned short v[8];
    if (f32io) {
        const float* Wf = (const float*)W;
        #pragma unroll
        for (int j = 0; j < 8; j++) v[j] = f2bf(Wf[(size_t)(krow + j) * HH + coln]);
    } else {
        const unsigned short* Wh = (const unsigned short*)W;
        #pragma unroll
        for (int j = 0; j < 8; j++) v[j] = Wh[(size_t)(krow + j) * HH + coln];
    }
    uint4 p;
    p.x = pk2(v[0], v[1]); p.y = pk2(v[2], v[3]);
    p.z = pk2(v[4], v[5]); p.w = pk2(v[6], v[7]);
    *(uint4*)(O + (size_t)g * 8) = p;
}

// ---- 2. k_DG: blocks [0,2500) O(d) LDS-bitmap dedupe + degree counts;
//  blocks [2500,3125) MFMA GEMM Y = x @ W1 (LDS-staged A, HW fp8 encode).
__global__ void k_DG(const void* x, const unsigned short* __restrict__ W1sw,
                     const int* flags, const int* rawcnt, int* cnt2,
                     unsigned short* bucket, unsigned char* Yf8, void* Oout) {
    __shared__ unsigned int bm[4][316];
    __shared__ int cnt[4];
    __shared__ unsigned short As[16][264];   // +8 pad
    int b = blockIdx.x;
    int tid = threadIdx.x;
    if (b < 2500) {
        // ---- dedupe: 4 rows/block, one wave each, wave-synchronous ----
        int wave = tid >> 6;
        int lane = tid & 63;
        int i = b * 4 + wave;
        int d = rawcnt[i];
        if (d > BKT) d = BKT;
        for (int t = lane; t < 313; t += 64) bm[wave][t] = 0u;
        if (lane == 0) cnt[wave] = 0;
        unsigned short* bp = bucket + (size_t)i * BKT;
        int cvals[3];
        int nt = 0;
        for (int t = lane; t < d; t += 64) cvals[nt++] = (int)bp[t];
        for (int k = 0; k < nt; k++) {
            int c = cvals[k];
            unsigned int m = 1u << (c & 31);
            unsigned int old = atomicOr(&bm[wave][c >> 5], m);
            if (!(old & m)) {
                int p = atomicAdd(&cnt[wave], 1);
                bp[p] = (unsigned short)c;
                atomicAdd(&cnt2[2 * c + 1], 1);      // deg_c
            }
        }
        if (lane == 0) atomicExch(&cnt2[2 * i], cnt[wave]);  // deg_r
        return;
    }
    // ---- GEMM branch ----
    int r0 = (b - 2500) * 16;
    int af32 = flags[1];
    {
        int row = tid >> 4, seg = tid & 15;
        if (af32) {
            const float* ap = (const float*)x + (size_t)(r0 + row) * HH + seg * 16;
            unsigned short v[16];
            #pragma unroll
            for (int j = 0; j < 16; j += 4) {
                float4 q = *(const float4*)(ap + j);
                v[j] = f2bf(q.x); v[j + 1] = f2bf(q.y);
                v[j + 2] = f2bf(q.z); v[j + 3] = f2bf(q.w);
            }
            uint4 p0, p1;
            p0.x = pk2(v[0], v[1]);   p0.y = pk2(v[2], v[3]);
            p0.z = pk2(v[4], v[5]);   p0.w = pk2(v[6], v[7]);
            p1.x = pk2(v[8], v[9]);   p1.y = pk2(v[10], v[11]);
            p1.z = pk2(v[12], v[13]); p1.w = pk2(v[14], v[15]);
            *(uint4*)&As[row][seg * 16] = p0;
            *(uint4*)&As[row][seg * 16 + 8] = p1;
        } else {
            const unsigned short* ap = (const unsigned short*)x + (size_t)(r0 + row) * HH + seg * 16;
            *(uint4*)&As[row][seg * 16] = *(const uint4*)ap;
            *(uint4*)&As[row][seg * 16 + 8] = *(const uint4*)(ap + 8);
        }
    }
    __syncthreads();
    int wv = tid >> 6;
    int lane = tid & 63;
    int quad = lane >> 4;
    int l16 = lane & 15;
    f32x4 acc[4] = {{0,0,0,0},{0,0,0,0},{0,0,0,0},{0,0,0,0}};
    for (int ks = 0; ks < 8; ks++) {
        bf16x8 af = *(const bf16x8*)&As[l16][ks * 32 + quad * 8];
        #pragma unroll
        for (int t = 0; t < 4; t++) {
            int n = wv * 4 + t;
            bf16x8 bf = *(const bf16x8*)(W1sw + ((size_t)(ks * 16 + n) * 64 + lane) * 8);
            acc[t] = __builtin_amdgcn_mfma_f32_16x16x32_bf16(af, bf, acc[t], 0, 0, 0);
        }
    }
    size_t chunkW = (size_t)NN * HH;
    #pragma unroll
    for (int t = 0; t < 4; t++) {
        int cn = (wv * 4 + t) * 16 + l16;
        #pragma unroll
        for (int r = 0; r < 4; r += 2) {
            int row = r0 + quad * 4 + r;
            float v0 = acc[t][r], v1 = acc[t][r + 1];
            unsigned int pk = fp8e2(v0, v1);
            size_t idx0 = (size_t)row * HH + cn;
            size_t idx1 = idx0 + HH;
            Yf8[idx0] = (unsigned char)(pk & 0xffu);
            Yf8[idx1] = (unsigned char)((pk >> 8) & 0xffu);
            if (af32) {
                ((float*)Oout)[2 * chunkW + idx0] = v0;
                ((float*)Oout)[2 * chunkW + idx1] = v1;
            } else {
                ((unsigned short*)Oout)[2 * chunkW + idx0] = f2bf(v0);
                ((unsigned short*)Oout)[2 * chunkW + idx1] = f2bf(v1);
            }
        }
    }
}

// ---- 3. k_CD: FUSED mid layer + stacked G GEMM. 1250 blocks x 512 thr;
//  block owns 8 node-rows, 1 row/wave, unroll-8 gather; neighbor indices
//  scalarized (readfirstlane) -> weight lookups via scalar cache.
//  G tables written PRE-SCALED; G1 stash (chunk 1) stays unscaled.
__global__ __launch_bounds__(512, 4) void k_CD(
        const unsigned char* __restrict__ Yf8,
        const unsigned short* __restrict__ bucket,
        const int* __restrict__ cnt2, const unsigned short* __restrict__ W2sw,
        const void* __restrict__ b1, const int* __restrict__ flags,
        unsigned char* G12f8, void* Oout) {
    __shared__ unsigned short Hs[16][264];   // +8 pad; rows 0..7 h1, 8..15 h2
    __shared__ float wsc[16];                // dinv_r (0..7) / dinv_c (8..15)
    int tid = threadIdx.x;
    int wave = tid >> 6;
    int lane = tid & 63;
    int fb = lane * 4;
    int bbase = blockIdx.x * 8;
    int f32io = flags[1];
    size_t chunkW = (size_t)NN * HH;
    float bv[4];
    if (f32io) {
        const float* bp = (const float*)b1 + fb;
        #pragma unroll
        for (int k = 0; k < 4; k++) bv[k] = bp[k];
    } else {
        uint2 br = *(const uint2*)((const unsigned short*)b1 + fb);
        bv[0] = bf2f(br.x & 0xffffu); bv[1] = bf2f(br.x >> 16);
        bv[2] = bf2f(br.y & 0xffffu); bv[3] = bf2f(br.y >> 16);
    }
    // ---- phase 1: SpMM, one row per wave, unroll 8, scalarized indices ----
    {
        int i = bbase + wave;
        float a1[4] = {0, 0, 0, 0};
        float a2[4] = {0, 0, 0, 0};
        int2 ddi = *(const int2*)(cnt2 + 2 * i);
        int n = ddi.x;
        const unsigned short* cp = bucket + (size_t)i * BKT;
        int t = 0;
        for (; t + 8 <= n; t += 8) {
            ushort4 ca = *(const ushort4*)(cp + t);
            ushort4 cb = *(const ushort4*)(cp + t + 4);
            int cx[8];
            cx[0] = rfl((int)ca.x); cx[1] = rfl((int)ca.y);
            cx[2] = rfl((int)ca.z); cx[3] = rfl((int)ca.w);
            cx[4] = rfl((int)cb.x); cx[5] = rfl((int)cb.y);
            cx[6] = rfl((int)cb.z); cx[7] = rfl((int)cb.w);
            unsigned int gv[8];
            #pragma unroll
            for (int j = 0; j < 8; j++)
                gv[j] = *(const unsigned int*)(Yf8 + (size_t)cx[j] * 256 + fb);
            float wx[8], wy[8];
            #pragma unroll
            for (int j = 0; j < 8; j++) {
                int2 dd = *(const int2*)(cnt2 + 2 * cx[j]);
                wx[j] = dinv_of(dd.x);
                wy[j] = dinv_of(dd.y);
            }
            #pragma unroll
            for (int j = 0; j < 8; j++) {
                float y[4];
                fp8dec4(gv[j], y);
                #pragma unroll
                for (int k = 0; k < 4; k++) {
                    a1[k] += wx[j] * y[k];
                    a2[k] += wy[j] * y[k];
                }
            }
        }
        for (; t + 4 <= n; t += 4) {
            ushort4 c4 = *(const ushort4*)(cp + t);
            int cx[4];
            cx[0] = rfl((int)c4.x); cx[1] = rfl((int)c4.y);
            cx[2] = rfl((int)c4.z); cx[3] = rfl((int)c4.w);
            unsigned int gv[4];
            #pragma unroll
            for (int j = 0; j < 4; j++)
                gv[j] = *(const unsigned int*)(Yf8 + (size_t)cx[j] * 256 + fb);
            float wx[4], wy[4];
            #pragma unroll
            for (int j = 0; j < 4; j++) {
                int2 dd = *(const int2*)(cnt2 + 2 * cx[j]);
                wx[j] = dinv_of(dd.x);
                wy[j] = dinv_of(dd.y);
            }
            #pragma unroll
            for (int j = 0; j < 4; j++) {
                float y[4];
                fp8dec4(gv[j], y);
                #pragma unroll
                for (int k = 0; k < 4; k++) {
                    a1[k] += wx[j] * y[k];
                    a2[k] += wy[j] * y[k];
                }
            }
        }
        for (; t < n; t++) {
            int c = rfl((int)cp[t]);
            int2 dd = *(const int2*)(cnt2 + 2 * c);
            float wx = dinv_of(dd.x);
            float wy = dinv_of(dd.y);
            unsigned int g = *(const unsigned int*)(Yf8 + (size_t)c * 256 + fb);
            float y[4];
            fp8dec4(g, y);
            #pragma unroll
            for (int k = 0; k < 4; k++) {
                a1[k] += wx * y[k];
                a2[k] += wy * y[k];
            }
        }
        float wiix = dinv_of(ddi.x);
        float wiiy = dinv_of(ddi.y);
        if (lane == 0) { wsc[wave] = wiix; wsc[8 + wave] = wiiy; }
        float yv[4];
        if (f32io) {
            const float* sp = (const float*)Oout + 2 * chunkW + (size_t)i * HH + fb;
            #pragma unroll
            for (int k = 0; k < 4; k++) yv[k] = sp[k];
        } else {
            uint2 yi = *(const uint2*)((const unsigned short*)Oout + 2 * chunkW + (size_t)i * HH + fb);
            yv[0] = bf2f(yi.x & 0xffffu); yv[1] = bf2f(yi.x >> 16);
            yv[2] = bf2f(yi.y & 0xffffu); yv[3] = bf2f(yi.y >> 16);
        }
        float h1[4], h2[4];
        #pragma unroll
        for (int k = 0; k < 4; k++) {
            h1[k] = fmaxf(0.f, yv[k] - wiix * a1[k] + bv[k]);
            h2[k] = fmaxf(0.f, wiiy * a2[k] + bv[k]);
        }
        uint2 p1, p2;
        p1.x = pk2(f2bf(h1[0]), f2bf(h1[1])); p1.y = pk2(f2bf(h1[2]), f2bf(h1[3]));
        p2.x = pk2(f2bf(h2[0]), f2bf(h2[1])); p2.y = pk2(f2bf(h2[2]), f2bf(h2[3]));
        *(uint2*)&Hs[wave][fb] = p1;
        *(uint2*)&Hs[8 + wave][fb] = p2;
    }
    __syncthreads();
    // ---- phase 2: one 16x256 MFMA GEMM of stacked [h1;h2] vs W2 ----
    int quad = lane >> 4;
    int l16 = lane & 15;
    f32x4 acc[2] = {{0,0,0,0},{0,0,0,0}};
    for (int ks = 0; ks < 8; ks++) {
        bf16x8 af = *(const bf16x8*)&Hs[l16][ks * 32 + quad * 8];
        #pragma unroll
        for (int t = 0; t < 2; t++) {
            int n = wave * 2 + t;
            bf16x8 bf = *(const bf16x8*)(W2sw + ((size_t)(ks * 16 + n) * 64 + lane) * 8);
            acc[t] = __builtin_amdgcn_mfma_f32_16x16x32_bf16(af, bf, acc[t], 0, 0, 0);
        }
    }
    #pragma unroll
    for (int t = 0; t < 2; t++) {
        int cn = (wave * 2 + t) * 16 + l16;
        #pragma unroll
        for (int r = 0; r < 4; r += 2) {
            int row16 = quad * 4 + r;
            float v0 = acc[t][r], v1 = acc[t][r + 1];
            unsigned int pk = fp8e2(wsc[row16] * v0, wsc[row16 + 1] * v1);
            if (row16 < 8) {                 // G1 rows: scaled table + unscaled stash
                int node = bbase + row16;
                G12f8[(size_t)node * 512 + cn] = (unsigned char)(pk & 0xffu);
                G12f8[(size_t)(node + 1) * 512 + cn] = (unsigned char)((pk >> 8) & 0xffu);
                size_t idx0 = (size_t)node * HH + cn;
                size_t idx1 = idx0 + HH;
                if (f32io) {
                    ((float*)Oout)[chunkW + idx0] = v0;
                    ((float*)Oout)[chunkW + idx1] = v1;
                } else {
                    ((unsigned short*)Oout)[chunkW + idx0] = f2bf(v0);
                    ((unsigned short*)Oout)[chunkW + idx1] = f2bf(v1);
                }
            } else {                         // G2 rows: scaled table
                int node = bbase + row16 - 8;
                G12f8[(size_t)node * 512 + 256 + cn] = (unsigned char)(pk & 0xffu);
                G12f8[(size_t)(node + 1) * 512 + 256 + cn] = (unsigned char)((pk >> 8) & 0xffu);
            }
        }
    }
}

// ---- 4. k_E: fused final layer (pure-sum gather on pre-scaled tables,
//  scalarized neighbor indices). launch_bounds (256,8): 64-VGPR cap ->
//  8 blocks/CU = 32 waves/CU for double latency hiding.
__global__ __launch_bounds__(256, 8) void k_E(
        const unsigned char* __restrict__ G12f8,
        const unsigned short* __restrict__ bucket,
        const int* __restrict__ cnt2, const void* __restrict__ bias,
        const int* __restrict__ flags, void* Oout) {
    int wave = threadIdx.x >> 6;
    int lane = threadIdx.x & 63;
    int half = lane >> 5;
    int sub = lane & 31;
    int fb = sub * 8;
    int goff = half * 256 + fb;
    int i = blockIdx.x * 4 + wave;
    float acc[8] = {0, 0, 0, 0, 0, 0, 0, 0};
    int2 ddi = *(const int2*)(cnt2 + 2 * i);
    int n = ddi.x;
    const unsigned short* cp = bucket + (size_t)i * BKT;
    int t = 0;
    for (; t + 8 <= n; t += 8) {
        ushort4 ca = *(const ushort4*)(cp + t);
        ushort4 cb = *(const ushort4*)(cp + t + 4);
        int cx[8];
        cx[0] = rfl((int)ca.x); cx[1] = rfl((int)ca.y);
        cx[2] = rfl((int)ca.z); cx[3] = rfl((int)ca.w);
        cx[4] = rfl((int)cb.x); cx[5] = rfl((int)cb.y);
        cx[6] = rfl((int)cb.z); cx[7] = rfl((int)cb.w);
        uint2 gv[8];
        #pragma unroll
        for (int j = 0; j < 8; j++)
            gv[j] = *(const uint2*)(G12f8 + (size_t)cx[j] * 512 + goff);
        #pragma unroll
        for (int j = 0; j < 8; j++) {
            float y[4], y2[4];
            fp8dec4(gv[j].x, y);
            fp8dec4(gv[j].y, y2);
            #pragma unroll
            for (int k = 0; k < 4; k++) {
                acc[k]     += y[k];
                acc[4 + k] += y2[k];
            }
        }
    }
    for (; t + 4 <= n; t += 4) {
        ushort4 c4 = *(const ushort4*)(cp + t);
        int cx[4];
        cx[0] = rfl((int)c4.x); cx[1] = rfl((int)c4.y);
        cx[2] = rfl((int)c4.z); cx[3] = rfl((int)c4.w);
        uint2 gv[4];
        #pragma unroll
        for (int j = 0; j < 4; j++)
            gv[j] = *(const uint2*)(G12f8 + (size_t)cx[j] * 512 + goff);
        #pragma unroll
        for (int j = 0; j < 4; j++) {
            float y[4], y2[4];
            fp8dec4(gv[j].x, y);
            fp8dec4(gv[j].y, y2);
            #pragma unroll
            for (int k = 0; k < 4; k++) {
                acc[k]     += y[k];
                acc[4 + k] += y2[k];
            }
        }
    }
    for (; t < n; t++) {
        int c = rfl((int)cp[t]);
        uint2 g = *(const uint2*)(G12f8 + (size_t)c * 512 + goff);
        float y[4], y2[4];
        fp8dec4(g.x, y);
        fp8dec4(g.y, y2);
        #pragma unroll
        for (int k = 0; k < 4; k++) {
            acc[k]     += y[k];
            acc[4 + k] += y2[k];
        }
    }
    int f32io = flags[1];
    float bv[8];
    if (f32io) {
        const float* bp = (const float*)bias + fb;
        #pragma unroll
        for (int k = 0; k < 8; k++) bv[k] = bp[k];
    } else {
        uint4 br = *(const uint4*)((const unsigned short*)bias + fb);
        bv[0] = bf2f(br.x & 0xffffu); bv[1] = bf2f(br.x >> 16);
        bv[2] = bf2f(br.y & 0xffffu); bv[3] = bf2f(br.y >> 16);
        bv[4] = bf2f(br.z & 0xffffu); bv[5] = bf2f(br.z >> 16);
        bv[6] = bf2f(br.w & 0xffffu); bv[7] = bf2f(br.w >> 16);
    }
    size_t base = (size_t)i * HH + fb;
    size_t chunkW = (size_t)NN * HH;
    float z[8];
    if (half == 0) {            // z1 = G1[i] - wr_i*sum + b -> chunk 1
        float wiix = dinv_of(ddi.x);
        float gvv[8];
        if (f32io) {
            const float* sp = (const float*)Oout + chunkW + base;
            #pragma unroll
            for (int k = 0; k < 8; k++) gvv[k] = sp[k];
        } else {
            uint4 gi = *(const uint4*)((const unsigned short*)Oout + chunkW + base);
            gvv[0] = bf2f(gi.x & 0xffffu); gvv[1] = bf2f(gi.x >> 16);
            gvv[2] = bf2f(gi.y & 0xffffu); gvv[3] = bf2f(gi.y >> 16);
            gvv[4] = bf2f(gi.z & 0xffffu); gvv[5] = bf2f(gi.z >> 16);
            gvv[6] = bf2f(gi.w & 0xffffu); gvv[7] = bf2f(gi.w >> 16);
        }
        #pragma unroll
        for (int k = 0; k < 8; k++) z[k] = gvv[k] - wiix * acc[k] + bv[k];
        if (f32io) {
            float* o = (float*)Oout + chunkW + base;
            *(float4*)o = make_float4(z[0], z[1], z[2], z[3]);
            *(float4*)(o + 4) = make_float4(z[4], z[5], z[6], z[7]);
        } else {
            uint4 p;
            p.x = pk2(f2bf(z[0]), f2bf(z[1])); p.y = pk2(f2bf(z[2]), f2bf(z[3]));
            p.z = pk2(f2bf(z[4]), f2bf(z[5])); p.w = pk2(f2bf(z[6]), f2bf(z[7]));
            *(uint4*)((unsigned short*)Oout + chunkW + base) = p;
        }
    } else {                    // z2 = wc_i*sum + b -> chunks 0, 2
        float wiiy = dinv_of(ddi.y);
        #pragma unroll
        for (int k = 0; k < 8; k++) z[k] = wiiy * acc[k] + bv[k];
        if (f32io) {
            float* o0 = (float*)Oout + base;
            float* o2 = (float*)Oout + 2 * chunkW + base;
            float4 pa = make_float4(z[0], z[1], z[2], z[3]);
            float4 pb = make_float4(z[4], z[5], z[6], z[7]);
            *(float4*)o0 = pa; *(float4*)(o0 + 4) = pb;
            *(float4*)o2 = pa; *(float4*)(o2 + 4) = pb;
        } else {
            uint4 p;
            p.x = pk2(f2bf(z[0]), f2bf(z[1])); p.y = pk2(f2bf(z[2]), f2bf(z[3]));
            p.z = pk2(f2bf(z[4]), f2bf(z[5])); p.w = pk2(f2bf(z[6]), f2bf(z[7]));
            *(uint4*)((unsigned short*)Oout + base) = p;
            *(uint4*)((unsigned short*)Oout + 2 * chunkW + base) = p;
        }
    }
}

extern "C" void kernel_launch(void* const* d_in, const int* in_sizes, int n_in,
                              void* d_out, int out_size, void* d_ws, size_t ws_size,
                              hipStream_t stream) {
    const void* x = 0; const void* ei = 0;
    const void* W1 = 0; const void* b1 = 0; const void* W2 = 0; const void* b2 = 0;
    for (int i = 0; i < n_in; i++) {
        int s = in_sizes[i];
        if (s == NN * HH) x = d_in[i];
        else if (s == 2 * EE) ei = d_in[i];
        else if (s == HH * HH) { if (!W1) W1 = d_in[i]; else W2 = d_in[i]; }
        else if (s == HH) { if (!b1) b1 = d_in[i]; else b2 = d_in[i]; }
    }

    char* ws = (char*)d_ws;
    size_t off = 0;
    int* flags = (int*)(ws + off); off += 256;
    int* rawcnt = (int*)(ws + off); off += 40960;   // raw per-row counts (padded)
    int* cnt2 = (int*)(ws + off); off += 81920;     // interleaved deg_r/deg_c (padded)
    unsigned short* bucket = (unsigned short*)(ws + off); off += (size_t)NN * BKT * 2;
    unsigned short* W1sw = (unsigned short*)(ws + off); off += (size_t)HH * HH * 2;
    unsigned short* W2sw = (unsigned short*)(ws + off); off += (size_t)HH * HH * 2;
    unsigned char* Yf8 = (unsigned char*)(ws + off); off += (size_t)NN * 256;
    unsigned char* G12f8 = (unsigned char*)(ws + off); off += (size_t)NN * 512;
    // total ~12 MB

    // 0. zero rawcnt+cnt2 (contiguous 120 KB; stream-ordered, graph-capturable)
    hipMemsetAsync(rawcnt, 0, 40960 + 81920, stream);
    // 1. detect + weight swizzle (self-detect) || raw edge scatter (self-detect)
    k_AB<<<65 + EE / 256, 256, 0, stream>>>(x, ei, W1, W2, flags, rawcnt, bucket,
                                            W1sw, W2sw);
    // 2. dedupe + degree counts || GEMM Y = x@W1 (fp8 table + stash)
    k_DG<<<2500 + 625, 256, 0, stream>>>(x, W1sw, flags, rawcnt, cnt2, bucket,
                                         Yf8, d_out);
    // 3. FUSED mid layer + stacked G GEMM (1 row/wave, unroll-8, scalarized)
    k_CD<<<NN / 8, 512, 0, stream>>>(Yf8, bucket, cnt2, W2sw, b1, flags, G12f8, d_out);
    // 4. fused final layer (pure-sum gather, unroll-8, occupancy-8)
    k_E<<<NN / 4, 256, 0, stream>>>(G12f8, bucket, cnt2, b2, flags, d_out);
}

// Round 14
// 170.093 us; speedup vs baseline: 1.0315x; 1.0093x over previous
//
#include <hip/hip_runtime.h>

#define NN 10000
#define EE 320000
#define HH 256
#define BKT 192          // per-row bucket capacity (raw deg ~Poisson(32), max ~65)

typedef __attribute__((ext_vector_type(8))) short bf16x8;
typedef __attribute__((ext_vector_type(4))) float f32x4;
typedef __attribute__((ext_vector_type(2))) float f32x2;

__device__ float bf2f(unsigned int v) {
    return __uint_as_float(v << 16);
}
__device__ unsigned short f2bf(float f) {
    unsigned int i = __float_as_uint(f);
    return (unsigned short)((i + 0x7fffu + ((i >> 16) & 1u)) >> 16);
}
// ---- software e4m3 codec (OCP-consistent; exact for normals, RNE) ----
__device__ unsigned int fp8e(float f) {
    float a = fabsf(f);
    a = fminf(a, 448.0f);
    unsigned int bits = __float_as_uint(a * __uint_as_float(0x03800000u)); // * 2^-120
    bits = bits + 0x7ffffu + ((bits >> 20) & 1u);
    unsigned int r = bits >> 20;
    if (r > 0x7eu) r = 0x7eu;
    return r | ((__float_as_uint(f) >> 24) & 0x80u);
}
__device__ float fp8d(unsigned int b) {
    float mag = __uint_as_float((b & 0x7fu) << 20) * __uint_as_float(0x7B800000u); // * 2^120
    return __uint_as_float(((b & 0x80u) << 24) | __float_as_uint(mag));
}
// ---- HW fp8->f32 decode: 4 packed e4m3 bytes -> 4 floats (2 instructions) ----
__device__ __forceinline__ void fp8dec4(unsigned int g, float* o) {
#if __has_builtin(__builtin_amdgcn_cvt_pk_f32_fp8)
    f32x2 lo = __builtin_amdgcn_cvt_pk_f32_fp8((int)g, false);
    f32x2 hi = __builtin_amdgcn_cvt_pk_f32_fp8((int)g, true);
    o[0] = lo.x; o[1] = lo.y; o[2] = hi.x; o[3] = hi.y;
#else
    #pragma unroll
    for (int j = 0; j < 4; j++) o[j] = fp8d((g >> (8 * j)) & 0xffu);
#endif
}
// ---- HW f32->fp8 encode: 2 floats -> 2 packed e4m3 bytes (1 instruction) ----
__device__ __forceinline__ unsigned int fp8e2(float a, float b) {
#if __has_builtin(__builtin_amdgcn_cvt_pk_fp8_f32)
    return (unsigned int)__builtin_amdgcn_cvt_pk_fp8_f32(a, b, 0, false);
#else
    return fp8e(a) | (fp8e(b) << 8);
#endif
}
__device__ unsigned int pk2(unsigned short a, unsigned short b) {
    return (unsigned int)a | ((unsigned int)b << 16);
}
__device__ int eload(const void* ei, int is64, int idx) {
    if (is64) return (int)(((const long long*)ei)[idx]);
    return ((const int*)ei)[idx];
}
__device__ __forceinline__ float dinv_of(int d) {
    return d > 0 ? rsqrtf((float)d) : 0.0f;
}
// wave-uniform index -> SGPR (neighbor lists are walked wave-synchronously)
__device__ __forceinline__ int rfl(int v) {
    return __builtin_amdgcn_readfirstlane(v);
}

// ---- 1. k_AB: blocks [0,1250) raw edge scatter FIRST (long pole; block-local
//  is64 detect); b==1250 detect flags; b in [1251,1315) weight swizzle
//  (block-local f32 detect). rawcnt/cnt2 pre-zeroed by hipMemsetAsync.
__global__ void k_AB(const void* x, const void* ei, const void* W1, const void* W2,
                     int* flags, int* rawcnt, unsigned short* bucket,
                     unsigned short* W1sw, unsigned short* W2sw) {
    int b = blockIdx.x, t = threadIdx.x;
    if (b < 1250) {
        // ---- raw scatter with block-local int64 detect ----
        __shared__ int s_nz;
        if (t == 0) s_nz = 0;
        __syncthreads();
        if (t < 64) {
            const unsigned int* eu = (const unsigned int*)ei;
            for (int k = t; k < 256; k += 64)
                if (eu[2 * k + 1] != 0) atomicOr(&s_nz, 1);
        }
        __syncthreads();
        int is64 = s_nz ? 0 : 1;
        int e = b * 256 + t;             // exactly EE threads
        if (e >= EE) return;
        int r = eload(ei, is64, e);
        int c = eload(ei, is64, EE + e);
        if (r < 0 || r >= NN || c < 0 || c >= NN) return;
        int slot = atomicAdd(&rawcnt[r], 1);
        if (slot < BKT) bucket[(size_t)r * BKT + slot] = (unsigned short)c;
        return;
    }
    if (b == 1250) {
        __shared__ int s0, s1;
        if (t == 0) { s0 = 0; s1 = 0; }
        __syncthreads();
        if (t < 64) {
            const unsigned int* eu = (const unsigned int*)ei;
            const unsigned int* xu = (const unsigned int*)x;
            for (int k = t; k < 256; k += 64)
                if (eu[2 * k + 1] != 0) atomicOr(&s0, 1);
            unsigned int lo = xu[t] & 0xffffu;
            unsigned int ex = (lo >> 7) & 0xffu;
            if (lo == 0u || (ex >= 90u && ex <= 150u)) atomicAdd(&s1, 1);
        }
        __syncthreads();
        if (t == 0) {
            flags[0] = s0 ? 0 : 1;          // edge_index is int64
            flags[1] = (s1 >= 56) ? 0 : 1;  // floats are f32
        }
        return;
    }
    // ---- weight swizzle with block-local f32 detect ----
    __shared__ int plaus;
    if (t == 0) plaus = 0;
    __syncthreads();
    if (t < 64) {
        unsigned int lo = ((const unsigned int*)x)[t] & 0xffffu;
        unsigned int ex = (lo >> 7) & 0xffu;
        if (lo == 0u || (ex >= 90u && ex <= 150u)) atomicAdd(&plaus, 1);
    }
    __syncthreads();
    int f32io = (plaus >= 56) ? 0 : 1;
    int vb = b - 1251;                   // 0..63
    const void* W = (vb < 32) ? W1 : W2;
    unsigned short* O = (vb < 32) ? W1sw : W2sw;
    int g = ((vb < 32) ? vb : vb - 32) * 256 + t;   // 8192 groups of 8
    int gl = g & 63;
    int n = (g >> 6) & 15;
    int ks = g >> 10;
    int coln = n * 16 + (gl & 15);
    int krow = ks * 32 + ((gl >> 4) & 3) * 8;
    unsigned short v[8];
    if (f32io) {
        const float* Wf = (const float*)W;
        #pragma unroll
        for (int j = 0; j < 8; j++) v[j] = f2bf(Wf[(size_t)(krow + j) * HH + coln]);
    } else {
        const unsigned short* Wh = (const unsigned short*)W;
        #pragma unroll
        for (int j = 0; j < 8; j++) v[j] = Wh[(size_t)(krow + j) * HH + coln];
    }
    uint4 p;
    p.x = pk2(v[0], v[1]); p.y = pk2(v[2], v[3]);
    p.z = pk2(v[4], v[5]); p.w = pk2(v[6], v[7]);
    *(uint4*)(O + (size_t)g * 8) = p;
}

// ---- 2. k_DG: blocks [0,625) MFMA GEMM Y = x @ W1 FIRST (long blocks lead
//  -> no low-occupancy GEMM tail); blocks [625,3125) O(d) LDS-bitmap dedupe.
__global__ void k_DG(const void* x, const unsigned short* __restrict__ W1sw,
                     const int* flags, const int* rawcnt, int* cnt2,
                     unsigned short* bucket, unsigned char* Yf8, void* Oout) {
    __shared__ unsigned int bm[4][316];
    __shared__ int cnt[4];
    __shared__ unsigned short As[16][264];   // +8 pad
    int b = blockIdx.x;
    int tid = threadIdx.x;
    if (b >= 625) {
        // ---- dedupe: 4 rows/block, one wave each, wave-synchronous ----
        int wave = tid >> 6;
        int lane = tid & 63;
        int i = (b - 625) * 4 + wave;
        int d = rawcnt[i];
        if (d > BKT) d = BKT;
        for (int t = lane; t < 313; t += 64) bm[wave][t] = 0u;
        if (lane == 0) cnt[wave] = 0;
        unsigned short* bp = bucket + (size_t)i * BKT;
        int cvals[3];
        int nt = 0;
        for (int t = lane; t < d; t += 64) cvals[nt++] = (int)bp[t];
        for (int k = 0; k < nt; k++) {
            int c = cvals[k];
            unsigned int m = 1u << (c & 31);
            unsigned int old = atomicOr(&bm[wave][c >> 5], m);
            if (!(old & m)) {
                int p = atomicAdd(&cnt[wave], 1);
                bp[p] = (unsigned short)c;
                atomicAdd(&cnt2[2 * c + 1], 1);      // deg_c
            }
        }
        if (lane == 0) atomicExch(&cnt2[2 * i], cnt[wave]);  // deg_r
        return;
    }
    // ---- GEMM branch ----
    int r0 = b * 16;
    int af32 = flags[1];
    {
        int row = tid >> 4, seg = tid & 15;
        if (af32) {
            const float* ap = (const float*)x + (size_t)(r0 + row) * HH + seg * 16;
            unsigned short v[16];
            #pragma unroll
            for (int j = 0; j < 16; j += 4) {
                float4 q = *(const float4*)(ap + j);
                v[j] = f2bf(q.x); v[j + 1] = f2bf(q.y);
                v[j + 2] = f2bf(q.z); v[j + 3] = f2bf(q.w);
            }
            uint4 p0, p1;
            p0.x = pk2(v[0], v[1]);   p0.y = pk2(v[2], v[3]);
            p0.z = pk2(v[4], v[5]);   p0.w = pk2(v[6], v[7]);
            p1.x = pk2(v[8], v[9]);   p1.y = pk2(v[10], v[11]);
            p1.z = pk2(v[12], v[13]); p1.w = pk2(v[14], v[15]);
            *(uint4*)&As[row][seg * 16] = p0;
            *(uint4*)&As[row][seg * 16 + 8] = p1;
        } else {
            const unsigned short* ap = (const unsigned short*)x + (size_t)(r0 + row) * HH + seg * 16;
            *(uint4*)&As[row][seg * 16] = *(const uint4*)ap;
            *(uint4*)&As[row][seg * 16 + 8] = *(const uint4*)(ap + 8);
        }
    }
    __syncthreads();
    int wv = tid >> 6;
    int lane = tid & 63;
    int quad = lane >> 4;
    int l16 = lane & 15;
    f32x4 acc[4] = {{0,0,0,0},{0,0,0,0},{0,0,0,0},{0,0,0,0}};
    for (int ks = 0; ks < 8; ks++) {
        bf16x8 af = *(const bf16x8*)&As[l16][ks * 32 + quad * 8];
        #pragma unroll
        for (int t = 0; t < 4; t++) {
            int n = wv * 4 + t;
            bf16x8 bf = *(const bf16x8*)(W1sw + ((size_t)(ks * 16 + n) * 64 + lane) * 8);
            acc[t] = __builtin_amdgcn_mfma_f32_16x16x32_bf16(af, bf, acc[t], 0, 0, 0);
        }
    }
    size_t chunkW = (size_t)NN * HH;
    #pragma unroll
    for (int t = 0; t < 4; t++) {
        int cn = (wv * 4 + t) * 16 + l16;
        #pragma unroll
        for (int r = 0; r < 4; r += 2) {
            int row = r0 + quad * 4 + r;
            float v0 = acc[t][r], v1 = acc[t][r + 1];
            unsigned int pk = fp8e2(v0, v1);
            size_t idx0 = (size_t)row * HH + cn;
            size_t idx1 = idx0 + HH;
            Yf8[idx0] = (unsigned char)(pk & 0xffu);
            Yf8[idx1] = (unsigned char)((pk >> 8) & 0xffu);
            if (af32) {
                ((float*)Oout)[2 * chunkW + idx0] = v0;
                ((float*)Oout)[2 * chunkW + idx1] = v1;
            } else {
                ((unsigned short*)Oout)[2 * chunkW + idx0] = f2bf(v0);
                ((unsigned short*)Oout)[2 * chunkW + idx1] = f2bf(v1);
            }
        }
    }
}

// ---- 3. k_CD: FUSED mid layer + stacked G GEMM. 1250 blocks x 512 thr;
//  block owns 8 node-rows, 1 row/wave, unroll-8 gather; neighbor indices
//  scalarized (readfirstlane) -> weight lookups via scalar cache.
//  G tables written PRE-SCALED; G1 stash (chunk 1) stays unscaled.
__global__ __launch_bounds__(512, 4) void k_CD(
        const unsigned char* __restrict__ Yf8,
        const unsigned short* __restrict__ bucket,
        const int* __restrict__ cnt2, const unsigned short* __restrict__ W2sw,
        const void* __restrict__ b1, const int* __restrict__ flags,
        unsigned char* G12f8, void* Oout) {
    __shared__ unsigned short Hs[16][264];   // +8 pad; rows 0..7 h1, 8..15 h2
    __shared__ float wsc[16];                // dinv_r (0..7) / dinv_c (8..15)
    int tid = threadIdx.x;
    int wave = tid >> 6;
    int lane = tid & 63;
    int fb = lane * 4;
    int bbase = blockIdx.x * 8;
    int f32io = flags[1];
    size_t chunkW = (size_t)NN * HH;
    float bv[4];
    if (f32io) {
        const float* bp = (const float*)b1 + fb;
        #pragma unroll
        for (int k = 0; k < 4; k++) bv[k] = bp[k];
    } else {
        uint2 br = *(const uint2*)((const unsigned short*)b1 + fb);
        bv[0] = bf2f(br.x & 0xffffu); bv[1] = bf2f(br.x >> 16);
        bv[2] = bf2f(br.y & 0xffffu); bv[3] = bf2f(br.y >> 16);
    }
    // ---- phase 1: SpMM, one row per wave, unroll 8, scalarized indices ----
    {
        int i = bbase + wave;
        float a1[4] = {0, 0, 0, 0};
        float a2[4] = {0, 0, 0, 0};
        int2 ddi = *(const int2*)(cnt2 + 2 * i);
        int n = ddi.x;
        const unsigned short* cp = bucket + (size_t)i * BKT;
        int t = 0;
        for (; t + 8 <= n; t += 8) {
            ushort4 ca = *(const ushort4*)(cp + t);
            ushort4 cb = *(const ushort4*)(cp + t + 4);
            int cx[8];
            cx[0] = rfl((int)ca.x); cx[1] = rfl((int)ca.y);
            cx[2] = rfl((int)ca.z); cx[3] = rfl((int)ca.w);
            cx[4] = rfl((int)cb.x); cx[5] = rfl((int)cb.y);
            cx[6] = rfl((int)cb.z); cx[7] = rfl((int)cb.w);
            unsigned int gv[8];
            #pragma unroll
            for (int j = 0; j < 8; j++)
                gv[j] = *(const unsigned int*)(Yf8 + (size_t)cx[j] * 256 + fb);
            float wx[8], wy[8];
            #pragma unroll
            for (int j = 0; j < 8; j++) {
                int2 dd = *(const int2*)(cnt2 + 2 * cx[j]);
                wx[j] = dinv_of(dd.x);
                wy[j] = dinv_of(dd.y);
            }
            #pragma unroll
            for (int j = 0; j < 8; j++) {
                float y[4];
                fp8dec4(gv[j], y);
                #pragma unroll
                for (int k = 0; k < 4; k++) {
                    a1[k] += wx[j] * y[k];
                    a2[k] += wy[j] * y[k];
                }
            }
        }
        for (; t + 4 <= n; t += 4) {
            ushort4 c4 = *(const ushort4*)(cp + t);
            int cx[4];
            cx[0] = rfl((int)c4.x); cx[1] = rfl((int)c4.y);
            cx[2] = rfl((int)c4.z); cx[3] = rfl((int)c4.w);
            unsigned int gv[4];
            #pragma unroll
            for (int j = 0; j < 4; j++)
                gv[j] = *(const unsigned int*)(Yf8 + (size_t)cx[j] * 256 + fb);
            float wx[4], wy[4];
            #pragma unroll
            for (int j = 0; j < 4; j++) {
                int2 dd = *(const int2*)(cnt2 + 2 * cx[j]);
                wx[j] = dinv_of(dd.x);
                wy[j] = dinv_of(dd.y);
            }
            #pragma unroll
            for (int j = 0; j < 4; j++) {
                float y[4];
                fp8dec4(gv[j], y);
                #pragma unroll
                for (int k = 0; k < 4; k++) {
                    a1[k] += wx[j] * y[k];
                    a2[k] += wy[j] * y[k];
                }
            }
        }
        for (; t < n; t++) {
            int c = rfl((int)cp[t]);
            int2 dd = *(const int2*)(cnt2 + 2 * c);
            float wx = dinv_of(dd.x);
            float wy = dinv_of(dd.y);
            unsigned int g = *(const unsigned int*)(Yf8 + (size_t)c * 256 + fb);
            float y[4];
            fp8dec4(g, y);
            #pragma unroll
            for (int k = 0; k < 4; k++) {
                a1[k] += wx * y[k];
                a2[k] += wy * y[k];
            }
        }
        float wiix = dinv_of(ddi.x);
        float wiiy = dinv_of(ddi.y);
        if (lane == 0) { wsc[wave] = wiix; wsc[8 + wave] = wiiy; }
        float yv[4];
        if (f32io) {
            const float* sp = (const float*)Oout + 2 * chunkW + (size_t)i * HH + fb;
            #pragma unroll
            for (int k = 0; k < 4; k++) yv[k] = sp[k];
        } else {
            uint2 yi = *(const uint2*)((const unsigned short*)Oout + 2 * chunkW + (size_t)i * HH + fb);
            yv[0] = bf2f(yi.x & 0xffffu); yv[1] = bf2f(yi.x >> 16);
            yv[2] = bf2f(yi.y & 0xffffu); yv[3] = bf2f(yi.y >> 16);
        }
        float h1[4], h2[4];
        #pragma unroll
        for (int k = 0; k < 4; k++) {
            h1[k] = fmaxf(0.f, yv[k] - wiix * a1[k] + bv[k]);
            h2[k] = fmaxf(0.f, wiiy * a2[k] + bv[k]);
        }
        uint2 p1, p2;
        p1.x = pk2(f2bf(h1[0]), f2bf(h1[1])); p1.y = pk2(f2bf(h1[2]), f2bf(h1[3]));
        p2.x = pk2(f2bf(h2[0]), f2bf(h2[1])); p2.y = pk2(f2bf(h2[2]), f2bf(h2[3]));
        *(uint2*)&Hs[wave][fb] = p1;
        *(uint2*)&Hs[8 + wave][fb] = p2;
    }
    __syncthreads();
    // ---- phase 2: one 16x256 MFMA GEMM of stacked [h1;h2] vs W2 ----
    int quad = lane >> 4;
    int l16 = lane & 15;
    f32x4 acc[2] = {{0,0,0,0},{0,0,0,0}};
    for (int ks = 0; ks < 8; ks++) {
        bf16x8 af = *(const bf16x8*)&Hs[l16][ks * 32 + quad * 8];
        #pragma unroll
        for (int t = 0; t < 2; t++) {
            int n = wave * 2 + t;
            bf16x8 bf = *(const bf16x8*)(W2sw + ((size_t)(ks * 16 + n) * 64 + lane) * 8);
            acc[t] = __builtin_amdgcn_mfma_f32_16x16x32_bf16(af, bf, acc[t], 0, 0, 0);
        }
    }
    #pragma unroll
    for (int t = 0; t < 2; t++) {
        int cn = (wave * 2 + t) * 16 + l16;
        #pragma unroll
        for (int r = 0; r < 4; r += 2) {
            int row16 = quad * 4 + r;
            float v0 = acc[t][r], v1 = acc[t][r + 1];
            unsigned int pk = fp8e2(wsc[row16] * v0, wsc[row16 + 1] * v1);
            if (row16 < 8) {                 // G1 rows: scaled table + unscaled stash
                int node = bbase + row16;
                G12f8[(size_t)node * 512 + cn] = (unsigned char)(pk & 0xffu);
                G12f8[(size_t)(node + 1) * 512 + cn] = (unsigned char)((pk >> 8) & 0xffu);
                size_t idx0 = (size_t)node * HH + cn;
                size_t idx1 = idx0 + HH;
                if (f32io) {
                    ((float*)Oout)[chunkW + idx0] = v0;
                    ((float*)Oout)[chunkW + idx1] = v1;
                } else {
                    ((unsigned short*)Oout)[chunkW + idx0] = f2bf(v0);
                    ((unsigned short*)Oout)[chunkW + idx1] = f2bf(v1);
                }
            } else {                         // G2 rows: scaled table
                int node = bbase + row16 - 8;
                G12f8[(size_t)node * 512 + 256 + cn] = (unsigned char)(pk & 0xffu);
                G12f8[(size_t)(node + 1) * 512 + 256 + cn] = (unsigned char)((pk >> 8) & 0xffu);
            }
        }
    }
}

// ---- 4. k_E: fused final layer (pure-sum gather on pre-scaled tables,
//  scalarized neighbor indices). launch_bounds (256,8).
__global__ __launch_bounds__(256, 8) void k_E(
        const unsigned char* __restrict__ G12f8,
        const unsigned short* __restrict__ bucket,
        const int* __restrict__ cnt2, const void* __restrict__ bias,
        const int* __restrict__ flags, void* Oout) {
    int wave = threadIdx.x >> 6;
    int lane = threadIdx.x & 63;
    int half = lane >> 5;
    int sub = lane & 31;
    int fb = sub * 8;
    int goff = half * 256 + fb;
    int i = blockIdx.x * 4 + wave;
    float acc[8] = {0, 0, 0, 0, 0, 0, 0, 0};
    int2 ddi = *(const int2*)(cnt2 + 2 * i);
    int n = ddi.x;
    const unsigned short* cp = bucket + (size_t)i * BKT;
    int t = 0;
    for (; t + 8 <= n; t += 8) {
        ushort4 ca = *(const ushort4*)(cp + t);
        ushort4 cb = *(const ushort4*)(cp + t + 4);
        int cx[8];
        cx[0] = rfl((int)ca.x); cx[1] = rfl((int)ca.y);
        cx[2] = rfl((int)ca.z); cx[3] = rfl((int)ca.w);
        cx[4] = rfl((int)cb.x); cx[5] = rfl((int)cb.y);
        cx[6] = rfl((int)cb.z); cx[7] = rfl((int)cb.w);
        uint2 gv[8];
        #pragma unroll
        for (int j = 0; j < 8; j++)
            gv[j] = *(const uint2*)(G12f8 + (size_t)cx[j] * 512 + goff);
        #pragma unroll
        for (int j = 0; j < 8; j++) {
            float y[4], y2[4];
            fp8dec4(gv[j].x, y);
            fp8dec4(gv[j].y, y2);
            #pragma unroll
            for (int k = 0; k < 4; k++) {
                acc[k]     += y[k];
                acc[4 + k] += y2[k];
            }
        }
    }
    for (; t + 4 <= n; t += 4) {
        ushort4 c4 = *(const ushort4*)(cp + t);
        int cx[4];
        cx[0] = rfl((int)c4.x); cx[1] = rfl((int)c4.y);
        cx[2] = rfl((int)c4.z); cx[3] = rfl((int)c4.w);
        uint2 gv[4];
        #pragma unroll
        for (int j = 0; j < 4; j++)
            gv[j] = *(const uint2*)(G12f8 + (size_t)cx[j] * 512 + goff);
        #pragma unroll
        for (int j = 0; j < 4; j++) {
            float y[4], y2[4];
            fp8dec4(gv[j].x, y);
            fp8dec4(gv[j].y, y2);
            #pragma unroll
            for (int k = 0; k < 4; k++) {
                acc[k]     += y[k];
                acc[4 + k] += y2[k];
            }
        }
    }
    for (; t < n; t++) {
        int c = rfl((int)cp[t]);
        uint2 g = *(const uint2*)(G12f8 + (size_t)c * 512 + goff);
        float y[4], y2[4];
        fp8dec4(g.x, y);
        fp8dec4(g.y, y2);
        #pragma unroll
        for (int k = 0; k < 4; k++) {
            acc[k]     += y[k];
            acc[4 + k] += y2[k];
        }
    }
    int f32io = flags[1];
    float bv[8];
    if (f32io) {
        const float* bp = (const float*)bias + fb;
        #pragma unroll
        for (int k = 0; k < 8; k++) bv[k] = bp[k];
    } else {
        uint4 br = *(const uint4*)((const unsigned short*)bias + fb);
        bv[0] = bf2f(br.x & 0xffffu); bv[1] = bf2f(br.x >> 16);
        bv[2] = bf2f(br.y & 0xffffu); bv[3] = bf2f(br.y >> 16);
        bv[4] = bf2f(br.z & 0xffffu); bv[5] = bf2f(br.z >> 16);
        bv[6] = bf2f(br.w & 0xffffu); bv[7] = bf2f(br.w >> 16);
    }
    size_t base = (size_t)i * HH + fb;
    size_t chunkW = (size_t)NN * HH;
    float z[8];
    if (half == 0) {            // z1 = G1[i] - wr_i*sum + b -> chunk 1
        float wiix = dinv_of(ddi.x);
        float gvv[8];
        if (f32io) {
            const float* sp = (const float*)Oout + chunkW + base;
            #pragma unroll
            for (int k = 0; k < 8; k++) gvv[k] = sp[k];
        } else {
            uint4 gi = *(const uint4*)((const unsigned short*)Oout + chunkW + base);
            gvv[0] = bf2f(gi.x & 0xffffu); gvv[1] = bf2f(gi.x >> 16);
            gvv[2] = bf2f(gi.y & 0xffffu); gvv[3] = bf2f(gi.y >> 16);
            gvv[4] = bf2f(gi.z & 0xffffu); gvv[5] = bf2f(gi.z >> 16);
            gvv[6] = bf2f(gi.w & 0xffffu); gvv[7] = bf2f(gi.w >> 16);
        }
        #pragma unroll
        for (int k = 0; k < 8; k++) z[k] = gvv[k] - wiix * acc[k] + bv[k];
        if (f32io) {
            float* o = (float*)Oout + chunkW + base;
            *(float4*)o = make_float4(z[0], z[1], z[2], z[3]);
            *(float4*)(o + 4) = make_float4(z[4], z[5], z[6], z[7]);
        } else {
            uint4 p;
            p.x = pk2(f2bf(z[0]), f2bf(z[1])); p.y = pk2(f2bf(z[2]), f2bf(z[3]));
            p.z = pk2(f2bf(z[4]), f2bf(z[5])); p.w = pk2(f2bf(z[6]), f2bf(z[7]));
            *(uint4*)((unsigned short*)Oout + chunkW + base) = p;
        }
    } else {                    // z2 = wc_i*sum + b -> chunks 0, 2
        float wiiy = dinv_of(ddi.y);
        #pragma unroll
        for (int k = 0; k < 8; k++) z[k] = wiiy * acc[k] + bv[k];
        if (f32io) {
            float* o0 = (float*)Oout + base;
            float* o2 = (float*)Oout + 2 * chunkW + base;
            float4 pa = make_float4(z[0], z[1], z[2], z[3]);
            float4 pb = make_float4(z[4], z[5], z[6], z[7]);
            *(float4*)o0 = pa; *(float4*)(o0 + 4) = pb;
            *(float4*)o2 = pa; *(float4*)(o2 + 4) = pb;
        } else {
            uint4 p;
            p.x = pk2(f2bf(z[0]), f2bf(z[1])); p.y = pk2(f2bf(z[2]), f2bf(z[3]));
            p.z = pk2(f2bf(z[4]), f2bf(z[5])); p.w = pk2(f2bf(z[6]), f2bf(z[7]));
            *(uint4*)((unsigned short*)Oout + base) = p;
            *(uint4*)((unsigned short*)Oout + 2 * chunkW + base) = p;
        }
    }
}

extern "C" void kernel_launch(void* const* d_in, const int* in_sizes, int n_in,
                              void* d_out, int out_size, void* d_ws, size_t ws_size,
                              hipStream_t stream) {
    const void* x = 0; const void* ei = 0;
    const void* W1 = 0; const void* b1 = 0; const void* W2 = 0; const void* b2 = 0;
    for (int i = 0; i < n_in; i++) {
        int s = in_sizes[i];
        if (s == NN * HH) x = d_in[i];
        else if (s == 2 * EE) ei = d_in[i];
        else if (s == HH * HH) { if (!W1) W1 = d_in[i]; else W2 = d_in[i]; }
        else if (s == HH) { if (!b1) b1 = d_in[i]; else b2 = d_in[i]; }
    }

    char* ws = (char*)d_ws;
    size_t off = 0;
    int* flags = (int*)(ws + off); off += 256;
    int* rawcnt = (int*)(ws + off); off += 40960;   // raw per-row counts (padded)
    int* cnt2 = (int*)(ws + off); off += 81920;     // interleaved deg_r/deg_c (padded)
    unsigned short* bucket = (unsigned short*)(ws + off); off += (size_t)NN * BKT * 2;
    unsigned short* W1sw = (unsigned short*)(ws + off); off += (size_t)HH * HH * 2;
    unsigned short* W2sw = (unsigned short*)(ws + off); off += (size_t)HH * HH * 2;
    unsigned char* Yf8 = (unsigned char*)(ws + off); off += (size_t)NN * 256;
    unsigned char* G12f8 = (unsigned char*)(ws + off); off += (size_t)NN * 512;
    // total ~12 MB

    // 0. zero rawcnt+cnt2 (contiguous 120 KB; stream-ordered, graph-capturable)
    hipMemsetAsync(rawcnt, 0, 40960 + 81920, stream);
    // 1. raw edge scatter FIRST (long pole) || detect || weight swizzle
    k_AB<<<1315, 256, 0, stream>>>(x, ei, W1, W2, flags, rawcnt, bucket,
                                   W1sw, W2sw);
    // 2. GEMM Y = x@W1 FIRST (long blocks) || dedupe + degree counts
    k_DG<<<3125, 256, 0, stream>>>(x, W1sw, flags, rawcnt, cnt2, bucket,
                                   Yf8, d_out);
    // 3. FUSED mid layer + stacked G GEMM (1 row/wave, unroll-8, scalarized)
    k_CD<<<NN / 8, 512, 0, stream>>>(Yf8, bucket, cnt2, W2sw, b1, flags, G12f8, d_out);
    // 4. fused final layer (pure-sum gather, unroll-8)
    k_E<<<NN / 4, 256, 0, stream>>>(G12f8, bucket, cnt2, b2, flags, d_out);
}